// Round 13
// baseline (768.414 us; speedup 1.0000x reference)
//
#include <hip/hip_runtime.h>
#include <hip/hip_bf16.h>
#include <math.h>

#define NPOS 16384   // B*H*W = 16*32*32
#define DD   512
#define PP   ((size_t)NPOS * DD)   // 8388608 elements per plane

typedef __bf16 bf16x8 __attribute__((ext_vector_type(8)));
typedef __bf16 bf16x4 __attribute__((ext_vector_type(4)));
typedef float  f32x4  __attribute__((ext_vector_type(4)));

// async global->LDS, 16 B per lane; LDS dest = wave-uniform base + lane*16
__device__ __forceinline__ void g2lds16(const void* g, void* l) {
  __builtin_amdgcn_global_load_lds(
      (__attribute__((address_space(1))) void*)g,
      (__attribute__((address_space(3))) void*)l, 16, 0, 0);
}

// ================= bf16 MFMA GEMM, 128x256 tile, double-buffered LDS =================
// C = A(MxK) @ Bt^T + bias.  A: MxK bf16 (ld K). Bt: NxK bf16 (ld K).
// R12 counters: 128x128 tile was barrier-drain bound (MfmaUtil 14%, all pipes idle).
// 128x256 doubles MFMA-per-barrier (32/wave/iter) against the same drain cost.
// 4 waves, each 64x128 (4x8 MFMA 16x16x32). LDS 16+32 KB dbuf. ~200 VGPR -> 2 blk/CU.
// Grid: blockIdx.x = M-tile (fastest) -> A-sharers same XCD (R11-verified FETCH cut).
// epi 0: C0 fp32 (ld N) = acc + bias
// epi 1: N=1024; cols<512 -> C1b bf16 (ld 512); cols>=512 -> sigmoid -> C1 bf16 (ld 512)
// epi 2: C0 fp32 (ld N) = acc + bias + res
__global__ __launch_bounds__(256, 2) void gemm_bf_k(
    const __bf16* __restrict__ A, const __bf16* __restrict__ Bt,
    const float* __restrict__ bias, const float* __restrict__ res,
    float* __restrict__ C0, __bf16* __restrict__ C1, __bf16* __restrict__ C1b,
    int N, int K, int epi)
{
  __shared__ __bf16 Asm[2][128 * 32];
  __shared__ __bf16 Bsm[2][256 * 32];
  const int tid  = threadIdx.x;
  const int wave = tid >> 6;
  const int lane = tid & 63;
  const int quad = lane >> 4;
  const int l16  = lane & 15;
  const int bm = blockIdx.x * 128;   // M fastest -> A-sharers on same XCD
  const int bn = blockIdx.y * 256;
  const int wm = (wave >> 1) << 6;
  const int wn = (wave & 1) << 7;    // 0 or 128

  const int srow   = lane >> 2;                                  // row within 16-row stage
  const int schunk = (((lane & 3) ^ ((lane >> 3) & 3)) << 3);    // swizzled k-chunk (elements)

  f32x4 acc[4][8];
  const f32x4 z4 = {0.f, 0.f, 0.f, 0.f};
  #pragma unroll
  for (int i = 0; i < 4; ++i)
    #pragma unroll
    for (int j = 0; j < 8; ++j) acc[i][j] = z4;

  const __bf16* Ab = A  + (size_t)bm * K;
  const __bf16* Bb = Bt + (size_t)bn * K;
  const int nk = K >> 5;

  #define STAGE(buf, kb)                                                              \
    {                                                                                 \
      const int k0s = (kb) << 5;                                                      \
      _Pragma("unroll")                                                               \
      for (int c = 0; c < 2; ++c) {                                                   \
        const int cc = wave * 2 + c;                                                  \
        g2lds16(Ab + (size_t)(cc * 16 + srow) * K + k0s + schunk, &Asm[buf][cc * 512]);\
      }                                                                               \
      _Pragma("unroll")                                                               \
      for (int c = 0; c < 4; ++c) {                                                   \
        const int cc = wave * 4 + c;                                                  \
        g2lds16(Bb + (size_t)(cc * 16 + srow) * K + k0s + schunk, &Bsm[buf][cc * 512]);\
      }                                                                               \
    }

  STAGE(0, 0)
  int cur = 0;
  for (int kb = 0; kb < nk; ++kb) {
    __syncthreads();
    if (kb + 1 < nk) STAGE(cur ^ 1, kb + 1)
    bf16x8 af[4], bg[8];
    #pragma unroll
    for (int i = 0; i < 4; ++i) {
      int m = wm + i * 16 + l16;
      af[i] = *(const bf16x8*)(&Asm[cur][m * 32 + ((quad ^ ((m >> 1) & 3)) << 3)]);
    }
    #pragma unroll
    for (int j = 0; j < 8; ++j) {
      int n = wn + j * 16 + l16;
      bg[j] = *(const bf16x8*)(&Bsm[cur][n * 32 + ((quad ^ ((n >> 1) & 3)) << 3)]);
    }
    #pragma unroll
    for (int i = 0; i < 4; ++i)
      #pragma unroll
      for (int j = 0; j < 8; ++j)
        acc[i][j] = __builtin_amdgcn_mfma_f32_16x16x32_bf16(af[i], bg[j], acc[i][j], 0, 0, 0);
    cur ^= 1;
  }
  #undef STAGE

  // epilogue. C/D layout: col = lane&15, row = quad*4 + reg  [m89-verified]
  const bool dosig = (epi == 1) && (bn >= 512);
  #pragma unroll
  for (int j = 0; j < 8; ++j) {
    const int col = wn + j * 16 + l16;
    const float bv = bias[bn + col];
    #pragma unroll
    for (int i = 0; i < 4; ++i) {
      const int row0 = bm + wm + i * 16 + quad * 4;
      #pragma unroll
      for (int r = 0; r < 4; ++r) {
        float v = acc[i][j][r] + bv;
        if (epi == 1) {
          if (dosig) {
            v = 1.f / (1.f + expf(-v));
            C1[(size_t)(row0 + r) * 512 + (bn - 512) + col] = (__bf16)v;
          } else {
            C1b[(size_t)(row0 + r) * 512 + bn + col] = (__bf16)v;
          }
        } else {
          size_t off = (size_t)(row0 + r) * N + bn + col;
          if (epi == 2) v += res[off];
          C0[off] = v;
        }
      }
    }
  }
}

// ---------------- fp32 -> bf16 elementwise (tokens) ----------------
__global__ __launch_bounds__(256) void cvt_k(const float* __restrict__ s, __bf16* __restrict__ d)
{
  size_t i = ((size_t)blockIdx.x * 256 + threadIdx.x) * 8;
  float4 a = *(const float4*)(s + i);
  float4 b = *(const float4*)(s + i + 4);
  bf16x8 v;
  v[0] = (__bf16)a.x; v[1] = (__bf16)a.y; v[2] = (__bf16)a.z; v[3] = (__bf16)a.w;
  v[4] = (__bf16)b.x; v[5] = (__bf16)b.y; v[6] = (__bf16)b.z; v[7] = (__bf16)b.w;
  *(bf16x8*)(d + i) = v;
}

// ---------------- transpose KxN fp32 -> NxK bf16 (weights) ----------------
__global__ __launch_bounds__(256) void tr_k(const float* __restrict__ src, __bf16* __restrict__ dst,
                                            int K, int N, size_t sstr, size_t dstr)
{
  __shared__ float t[32][33];
  const float* s = src + blockIdx.z * sstr;
  __bf16* d = dst + blockIdx.z * dstr;
  int n0 = blockIdx.x * 32, k0 = blockIdx.y * 32;
  int tx = threadIdx.x & 31, ty = threadIdx.x >> 5;   // 32x8
  #pragma unroll
  for (int i = 0; i < 4; ++i)
    t[ty + i * 8][tx] = s[(size_t)(k0 + ty + i * 8) * N + n0 + tx];
  __syncthreads();
  #pragma unroll
  for (int i = 0; i < 4; ++i)
    d[(size_t)(n0 + ty + i * 8) * K + k0 + tx] = (__bf16)t[tx][ty + i * 8];
}

// ---------------- LayerNorm over D=512, one wave per position, bf16 out ----------------
__global__ __launch_bounds__(256) void ln_k(const float* __restrict__ x, const float* __restrict__ w,
                                            const float* __restrict__ bv, __bf16* __restrict__ out)
{
  int gw = (blockIdx.x * 256 + threadIdx.x) >> 6;   // position
  int lane = threadIdx.x & 63;
  const float* xp = x + ((size_t)gw << 9) + lane * 8;
  float4 u0 = *(const float4*)xp;
  float4 u1 = *(const float4*)(xp + 4);
  float v[8] = {u0.x,u0.y,u0.z,u0.w,u1.x,u1.y,u1.z,u1.w};
  float s = 0.f;
  #pragma unroll
  for (int j = 0; j < 8; ++j) s += v[j];
  #pragma unroll
  for (int off = 32; off; off >>= 1) s += __shfl_xor(s, off, 64);
  float mu = s * (1.f/512.f);
  float q = 0.f;
  #pragma unroll
  for (int j = 0; j < 8; ++j) { float d = v[j] - mu; q += d*d; }
  #pragma unroll
  for (int off = 32; off; off >>= 1) q += __shfl_xor(q, off, 64);
  float rstd = rsqrtf(q * (1.f/512.f) + 1e-5f);
  int dch = lane * 8;
  float4 w0 = *(const float4*)(w + dch),  w1 = *(const float4*)(w + dch + 4);
  float4 b0 = *(const float4*)(bv + dch), b1 = *(const float4*)(bv + dch + 4);
  float wv[8] = {w0.x,w0.y,w0.z,w0.w,w1.x,w1.y,w1.z,w1.w};
  float bb[8] = {b0.x,b0.y,b0.z,b0.w,b1.x,b1.y,b1.z,b1.w};
  bf16x8 ov;
  #pragma unroll
  for (int j = 0; j < 8; ++j) ov[j] = (__bf16)((v[j] - mu) * rstd * wv[j] + bb[j]);
  *(bf16x8*)(out + ((size_t)gw << 9) + dch) = ov;
}

// ================= Fully-fused conv + 2D scan, chunk-interleaved =================
// R12 proved fusion wins (unfusing cost +44 µs). This is R11's fused kernel with 2x
// ILP: both thread-owned chunks (c0, c0+16) interleaved in every serial phase -> two
// independent FMA/LDS chains per loop (R11 VALUBusy was 51% = half stalled on deps).
// LDS: T (xin tile -> partial park, 64 KB) + Y (u tile, 64 KB) + S (16 KB) = 144 KB.
// Bounded unroll 4 everywhere (R9/R10: scheduler cross-loop load batching spills).
__device__ __forceinline__ float sig_a(float al) {
  float a = 1.f / (1.f + expf(-al));
  return fminf(fmaxf(a, 1e-4f), 1.f - 1e-4f);
}

__global__ __launch_bounds__(512, 2) void scan2d_k(
    const __bf16* __restrict__ xin, const float* __restrict__ cw, const float* __restrict__ cb,
    const float* __restrict__ alog, const float* __restrict__ bvec, const float* __restrict__ cvec,
    const float* __restrict__ dvec, const __bf16* __restrict__ gate, __bf16* __restrict__ yo)
{
  __shared__ __bf16 T[32768];       // xin tile [pos][32 ch]; partial park in phase C. 64 KB
  __shared__ __bf16 Y[32768];       // u tile. 64 KB
  __shared__ float  S[4][32][32];   // chunk sums: rowF,rowB,colF,colB. 16 KB
  const int tid = threadIdx.x;
  const int cg  = blockIdx.x;       // channel group of 32
  const int b   = blockIdx.y;
  const int ch  = tid & 31;
  const int c0  = tid >> 5;         // 0..15; thread owns chunks c0 and c0+16
  const int c1  = c0 + 16;
  const int d   = (cg << 5) + ch;

  const float a   = sig_a(alog[d]);
  const float lna = logf(a);
  const float ia  = 1.f / a;
  const float bb  = bvec[d];
  const float sc  = 0.25f * cvec[d];
  const float dd  = dvec[d];

  const __bf16* ub = xin + ((size_t)b << 19) + (cg << 5);

  // ---- load xin tile: 8 x bf16x8 per thread, 16 B/lane coalesced ----
  #pragma unroll
  for (int i = 0; i < 8; ++i) {
    int flat = (tid + i * 512) << 3;
    int pos = flat >> 5;
    int c8  = flat & 31;
    *(bf16x8*)(T + flat) = *(const bf16x8*)(ub + (size_t)pos * 512 + c8);
  }
  // conv weights while loads are in flight
  float w00 = cw[(0 << 9) + d], w01 = cw[(1 << 9) + d], w02 = cw[(2 << 9) + d];
  float w10 = cw[(3 << 9) + d], w11 = cw[(4 << 9) + d], w12 = cw[(5 << 9) + d];
  float w20 = cw[(6 << 9) + d], w21 = cw[(7 << 9) + d], w22 = cw[(8 << 9) + d];
  const float cbv = cb[d];
  // scan bases (loop-invariant; direct expf avoids 0*inf at extreme a)
  const float A0f = expf((float)(c0 << 5) * lna),        R0f = expf((float)(c0 << 5) * -lna);
  const float A1f = expf((float)(c1 << 5) * lna),        R1f = expf((float)(c1 << 5) * -lna);
  const float A0b = expf((float)((31 - c0) << 5) * lna), R0b = expf((float)((31 - c0) << 5) * -lna);
  const float A1b = expf((float)((31 - c1) << 5) * lna), R1b = expf((float)((31 - c1) << 5) * -lna);
  __syncthreads();

  // ---- phase 0: depthwise 3x3 conv + SiLU, rows c0 & c1 interleaved -> Y ----
  {
    const bool up0 = (c0 > 0);      // row c0-1 valid (c0+1 always <= 16 valid)
    const bool dn1 = (c0 < 15);     // row c1+1 valid (c1-1 always >= 15 valid)
    float a0 = 0.f, a1 = 0.f, a2 = 0.f, f0 = 0.f, f1 = 0.f, f2 = 0.f;   // col -1
    float b0 = up0 ? (float)T[(((c0 - 1) << 5)) * 32 + ch] : 0.f;        // col 0
    float b1 =        (float)T[((c0 << 5)) * 32 + ch];
    float b2 =        (float)T[(((c0 + 1) << 5)) * 32 + ch];
    float g0 =        (float)T[(((c1 - 1) << 5)) * 32 + ch];
    float g1 =        (float)T[((c1 << 5)) * 32 + ch];
    float g2 = dn1 ? (float)T[(((c1 + 1) << 5)) * 32 + ch] : 0.f;
    #pragma unroll 4
    for (int ww = 0; ww < 32; ++ww) {
      float e0 = 0.f, e1 = 0.f, e2 = 0.f, i0 = 0.f, i1 = 0.f, i2 = 0.f;  // col ww+1
      if (ww < 31) {
        e0 = up0 ? (float)T[(((c0 - 1) << 5) + ww + 1) * 32 + ch] : 0.f;
        e1 =        (float)T[((c0 << 5) + ww + 1) * 32 + ch];
        e2 =        (float)T[(((c0 + 1) << 5) + ww + 1) * 32 + ch];
        i0 =        (float)T[(((c1 - 1) << 5) + ww + 1) * 32 + ch];
        i1 =        (float)T[((c1 << 5) + ww + 1) * 32 + ch];
        i2 = dn1 ? (float)T[(((c1 + 1) << 5) + ww + 1) * 32 + ch] : 0.f;
      }
      float acc0 = cbv, acc1 = cbv;
      acc0 = fmaf(a0, w00, acc0); acc0 = fmaf(b0, w01, acc0); acc0 = fmaf(e0, w02, acc0);
      acc0 = fmaf(a1, w10, acc0); acc0 = fmaf(b1, w11, acc0); acc0 = fmaf(e1, w12, acc0);
      acc0 = fmaf(a2, w20, acc0); acc0 = fmaf(b2, w21, acc0); acc0 = fmaf(e2, w22, acc0);
      acc1 = fmaf(f0, w00, acc1); acc1 = fmaf(g0, w01, acc1); acc1 = fmaf(i0, w02, acc1);
      acc1 = fmaf(f1, w10, acc1); acc1 = fmaf(g1, w11, acc1); acc1 = fmaf(i1, w12, acc1);
      acc1 = fmaf(f2, w20, acc1); acc1 = fmaf(g2, w21, acc1); acc1 = fmaf(i2, w22, acc1);
      acc0 = acc0 / (1.f + expf(-acc0));
      acc1 = acc1 / (1.f + expf(-acc1));
      Y[((c0 << 5) + ww) * 32 + ch] = (__bf16)acc0;
      Y[((c1 << 5) + ww) * 32 + ch] = (__bf16)acc1;
      a0 = b0; a1 = b1; a2 = b2; b0 = e0; b1 = e1; b2 = e2;
      f0 = g0; f1 = g1; f2 = g2; g0 = i0; g1 = i1; g2 = i2;
    }
  }
  __syncthreads();

  // one scan step: r += u*bb/max(apr,1e-20) with tracked reciprocal
  #define STEP(r_, uu_, apr_, rp_)                                 \
    { float rr_ = (apr_ < 1e-20f) ? 1e20f : rp_;                   \
      r_ = fmaf((uu_) * bb, rr_, r_); }

  // ---- phase A: 8 chunk sums (2 chunks x rowF/rowB/colF/colB) in one loop ----
  {
    float p0 = A0f, q0 = R0f, p0B = A0b, q0B = R0b;
    float p1 = A1f, q1 = R1f, p1B = A1b, q1B = R1b;
    float s0 = 0.f, s1 = 0.f, s2 = 0.f, s3 = 0.f;
    float s4 = 0.f, s5 = 0.f, s6 = 0.f, s7 = 0.f;
    #pragma unroll 4
    for (int j = 0; j < 32; ++j) {
      float u0rf = (float)Y[((c0 << 5) + j) * 32 + ch];
      float u0rb = (float)Y[((c0 << 5) + (31 - j)) * 32 + ch];
      float u0cf = (float)Y[((j << 5) | c0) * 32 + ch];
      float u0cb = (float)Y[(((31 - j) << 5) | c0) * 32 + ch];
      float u1rf = (float)Y[((c1 << 5) + j) * 32 + ch];
      float u1rb = (float)Y[((c1 << 5) + (31 - j)) * 32 + ch];
      float u1cf = (float)Y[((j << 5) | c1) * 32 + ch];
      float u1cb = (float)Y[(((31 - j) << 5) | c1) * 32 + ch];
      STEP(s0, u0rf, p0, q0)  STEP(s2, u0cf, p0, q0)
      STEP(s1, u0rb, p0B, q0B) STEP(s3, u0cb, p0B, q0B)
      STEP(s4, u1rf, p1, q1)  STEP(s6, u1cf, p1, q1)
      STEP(s5, u1rb, p1B, q1B) STEP(s7, u1cb, p1B, q1B)
      p0 *= a; q0 *= ia; p0B *= a; q0B *= ia;
      p1 *= a; q1 *= ia; p1B *= a; q1B *= ia;
    }
    S[0][c0][ch] = s0; S[1][c0][ch] = s1; S[2][c0][ch] = s2; S[3][c0][ch] = s3;
    S[0][c1][ch] = s4; S[1][c1][ch] = s5; S[2][c1][ch] = s6; S[3][c1][ch] = s7;
  }
  __syncthreads();

  // ---- phase B: exclusive prefix (F arrays) / exclusive suffix (B arrays) ----
  if (tid < 128) {
    int arr = tid >> 5, ch2 = tid & 31;
    float run = 0.f;
    if ((arr & 1) == 0) {
      #pragma unroll 4
      for (int cc = 0; cc < 32; ++cc) { float v = S[arr][cc][ch2]; S[arr][cc][ch2] = run; run += v; }
    } else {
      #pragma unroll 4
      for (int cc = 31; cc >= 0; --cc) { float v = S[arr][cc][ch2]; S[arr][cc][ch2] = run; run += v; }
    }
  }
  __syncthreads();

  // ---- C-col fwd (both chunks): raw partial -> T ----
  {
    float r0 = S[2][c0][ch], r1 = S[2][c1][ch];
    float p0 = A0f, q0 = R0f, p1 = A1f, q1 = R1f;
    #pragma unroll 4
    for (int j = 0; j < 32; ++j) {
      int i0 = ((j << 5) | c0) * 32 + ch, i1 = ((j << 5) | c1) * 32 + ch;
      float u0 = (float)Y[i0], u1 = (float)Y[i1];
      float ap0 = fmaxf(p0, 1e-20f), ap1 = fmaxf(p1, 1e-20f);
      STEP(r0, u0, p0, q0) STEP(r1, u1, p1, q1)
      T[i0] = (__bf16)(r0 * ap0);
      T[i1] = (__bf16)(r1 * ap1);
      p0 *= a; q0 *= ia; p1 *= a; q1 *= ia;
    }
  }
  // ---- C-col bwd (both chunks): T = sc*(T + r*ap)  [same-thread RMW] ----
  {
    float r0 = S[3][c0][ch], r1 = S[3][c1][ch];
    float p0 = A0b, q0 = R0b, p1 = A1b, q1 = R1b;
    #pragma unroll 4
    for (int j = 31; j >= 0; --j) {
      int i0 = ((j << 5) | c0) * 32 + ch, i1 = ((j << 5) | c1) * 32 + ch;
      float u0 = (float)Y[i0], u1 = (float)Y[i1];
      float ap0 = fmaxf(p0, 1e-20f), ap1 = fmaxf(p1, 1e-20f);
      STEP(r0, u0, p0, q0) STEP(r1, u1, p1, q1)
      T[i0] = (__bf16)(sc * ((float)T[i0] + r0 * ap0));
      T[i1] = (__bf16)(sc * ((float)T[i1] + r1 * ap1));
      p0 *= a; q0 *= ia; p1 *= a; q1 *= ia;
    }
  }
  __syncthreads();   // row threads read other threads' col finals

  // ---- C-row fwd (both chunks): T += sc*(r*ap) ----
  {
    float r0 = S[0][c0][ch], r1 = S[0][c1][ch];
    float p0 = A0f, q0 = R0f, p1 = A1f, q1 = R1f;
    #pragma unroll 4
    for (int j = 0; j < 32; ++j) {
      int i0 = ((c0 << 5) + j) * 32 + ch, i1 = ((c1 << 5) + j) * 32 + ch;
      float u0 = (float)Y[i0], u1 = (float)Y[i1];
      float ap0 = fmaxf(p0, 1e-20f), ap1 = fmaxf(p1, 1e-20f);
      STEP(r0, u0, p0, q0) STEP(r1, u1, p1, q1)
      T[i0] = (__bf16)((float)T[i0] + sc * (r0 * ap0));
      T[i1] = (__bf16)((float)T[i1] + sc * (r1 * ap1));
      p0 *= a; q0 *= ia; p1 *= a; q1 *= ia;
    }
  }
  // ---- C-row bwd (both chunks): finalize + d*u, *gate, write out ----
  {
    const __bf16* gb = gate + ((size_t)b << 19) + (cg << 5) + ch;
    __bf16* yb = yo + ((size_t)b << 19) + (cg << 5) + ch;
    float r0 = S[1][c0][ch], r1 = S[1][c1][ch];
    float p0 = A0b, q0 = R0b, p1 = A1b, q1 = R1b;
    #pragma unroll 4
    for (int j = 31; j >= 0; --j) {
      int pp0 = (c0 << 5) + j, pp1 = (c1 << 5) + j;
      int i0 = pp0 * 32 + ch, i1 = pp1 * 32 + ch;
      float u0 = (float)Y[i0], u1 = (float)Y[i1];
      float ap0 = fmaxf(p0, 1e-20f), ap1 = fmaxf(p1, 1e-20f);
      STEP(r0, u0, p0, q0) STEP(r1, u1, p1, q1)
      float y0 = (float)T[i0] + sc * (r0 * ap0) + dd * u0;
      float y1 = (float)T[i1] + sc * (r1 * ap1) + dd * u1;
      yb[(size_t)pp0 * 512] = (__bf16)(y0 * (float)gb[(size_t)pp0 * 512]);
      yb[(size_t)pp1 * 512] = (__bf16)(y1 * (float)gb[(size_t)pp1 * 512]);
      p0 *= a; q0 *= ia; p1 *= a; q1 *= ia;
    }
  }
  #undef STEP
}

// ---------------- mean over 1024 positions (bf16 in) -> (16, 512) fp32 ----------------
__global__ __launch_bounds__(64) void reduce_k(const __bf16* __restrict__ hn, float* __restrict__ out)
{
  int d = blockIdx.y * 64 + threadIdx.x;
  int b = blockIdx.x;
  const __bf16* p = hn + ((size_t)b << 19) + d;
  float s0 = 0.f, s1 = 0.f, s2 = 0.f, s3 = 0.f;
  for (int t = 0; t < 1024; t += 4) {
    s0 += (float)p[(size_t)(t+0) << 9];
    s1 += (float)p[(size_t)(t+1) << 9];
    s2 += (float)p[(size_t)(t+2) << 9];
    s3 += (float)p[(size_t)(t+3) << 9];
  }
  out[b * 512 + d] = (s0 + s1 + s2 + s3) * (1.f / 1024.f);
}

extern "C" void kernel_launch(void* const* d_in, const int* in_sizes, int n_in,
                              void* d_out, int out_size, void* d_ws, size_t ws_size,
                              hipStream_t stream)
{
  const float* tokens = (const float*)d_in[0];
  const float* in_w   = (const float*)d_in[1];
  const float* in_b   = (const float*)d_in[2];
  const float* nw     = (const float*)d_in[3];
  const float* nb     = (const float*)d_in[4];
  const float* iw     = (const float*)d_in[5];
  const float* ib     = (const float*)d_in[6];
  const float* cw     = (const float*)d_in[7];
  const float* cb     = (const float*)d_in[8];
  const float* al     = (const float*)d_in[9];
  const float* bbv    = (const float*)d_in[10];
  const float* ccv    = (const float*)d_in[11];
  const float* ddv    = (const float*)d_in[12];
  const float* ow     = (const float*)d_in[13];
  const float* obv    = (const float*)d_in[14];
  const float* onw    = (const float*)d_in[15];
  const float* onb    = (const float*)d_in[16];

  // workspace layout (~115 MB):
  float*  x     = (float*)d_ws;                      // fp32 residual (33.5 MB)
  __bf16* hy16  = (__bf16*)(x + PP);                 // bf16 h / yg / final-ln (16.8 MB)
  __bf16* xin16 = hy16 + PP;                         // bf16 x_in (16.8 MB)
  __bf16* g16   = xin16 + PP;                        // bf16 gate (16.8 MB)
  __bf16* iwT   = g16 + PP;                          // 4x(1024x512) bf16 (4.2 MB)
  __bf16* owT   = iwT + (size_t)4 * 1024 * 512;      // 4x(512x512) bf16 (2.1 MB)
  __bf16* tb16  = owT + (size_t)4 * 512 * 512;       // tokens bf16 (25.2 MB)
  __bf16* inwT  = xin16;                             // in_proj_w^T bf16 (pre-loop alias)

  // --- weight/input conversion (once per launch) ---
  cvt_k<<<6144, 256, 0, stream>>>(tokens, tb16);
  tr_k<<<dim3(16, 24, 1), 256, 0, stream>>>(in_w, inwT, 768, 512, 0, 0);
  tr_k<<<dim3(32, 16, 4), 256, 0, stream>>>(iw, iwT, 512, 1024, (size_t)512*1024, (size_t)1024*512);
  tr_k<<<dim3(16, 16, 4), 256, 0, stream>>>(ow, owT, 512, 512, (size_t)512*512, (size_t)512*512);

  // x = tokens @ in_proj_w + b   (grid: M-tiles fastest)
  gemm_bf_k<<<dim3(128, 2), 256, 0, stream>>>(tb16, inwT, in_b, nullptr, x, nullptr, nullptr,
                                              512, 768, 0);

  for (int i = 0; i < 4; ++i) {
    ln_k<<<4096, 256, 0, stream>>>(x, nw + i*512, nb + i*512, hy16);
    gemm_bf_k<<<dim3(128, 4), 256, 0, stream>>>(hy16, iwT + (size_t)i*1024*512, ib + i*1024,
                                                nullptr, nullptr, g16, xin16, 1024, 512, 1);
    scan2d_k<<<dim3(16, 16), 512, 0, stream>>>(xin16, cw + i*9*512, cb + i*512,
                                               al + i*512, bbv + i*512, ccv + i*512,
                                               ddv + i*512, g16, hy16);
    gemm_bf_k<<<dim3(128, 2), 256, 0, stream>>>(hy16, owT + (size_t)i*512*512, obv + i*512,
                                                x, x, nullptr, nullptr, 512, 512, 2);
  }

  ln_k<<<4096, 256, 0, stream>>>(x, onw, onb, hy16);
  reduce_k<<<dim3(16, 8), 64, 0, stream>>>(hy16, (float*)d_out);
}

// Round 14
// 651.535 us; speedup vs baseline: 1.1794x; 1.1794x over previous
//
#include <hip/hip_runtime.h>
#include <hip/hip_bf16.h>
#include <math.h>

#define NPOS 16384   // B*H*W = 16*32*32
#define DD   512
#define PP   ((size_t)NPOS * DD)   // 8388608 elements per plane

typedef __bf16 bf16x8 __attribute__((ext_vector_type(8)));
typedef __bf16 bf16x4 __attribute__((ext_vector_type(4)));
typedef float  f32x4  __attribute__((ext_vector_type(4)));

// async global->LDS, 16 B per lane; LDS dest = wave-uniform base + lane*16
__device__ __forceinline__ void g2lds16(const void* g, void* l) {
  __builtin_amdgcn_global_load_lds(
      (__attribute__((address_space(1))) void*)g,
      (__attribute__((address_space(3))) void*)l, 16, 0, 0);
}

// ================= bf16 MFMA GEMM, 128x128, double-buffered LDS (R12-proven) =================
// R13 lesson: 128x256 tile regressed (MfmaUtil 14->5.6%): barrier drains ALL outstanding
// global_load_lds, so more loads per iter = longer drain, and regs/LDS cut residency to
// 1-2 blocks/CU — killing the cross-block overlap that actually hides the drain.
// Grid: blockIdx.x = M-tile (fastest) -> A-sharers same XCD (R11/R12-verified FETCH cut).
// epi 0: C0 fp32 (ld N) = acc + bias
// epi 1: N=1024; cols<512 -> C1b bf16 (ld 512); cols>=512 -> sigmoid -> C1 bf16 (ld 512)
// epi 2: C0 fp32 (ld N) = acc + bias + res
__global__ __launch_bounds__(256, 3) void gemm_bf_k(
    const __bf16* __restrict__ A, const __bf16* __restrict__ Bt,
    const float* __restrict__ bias, const float* __restrict__ res,
    float* __restrict__ C0, __bf16* __restrict__ C1, __bf16* __restrict__ C1b,
    int N, int K, int epi)
{
  __shared__ __bf16 Asm[2][128 * 32];
  __shared__ __bf16 Bsm[2][128 * 32];
  const int tid  = threadIdx.x;
  const int wave = tid >> 6;
  const int lane = tid & 63;
  const int quad = lane >> 4;
  const int l16  = lane & 15;
  const int bm = blockIdx.x * 128;   // M fastest -> A-sharers on same XCD
  const int bn = blockIdx.y * 128;
  const int wm = (wave >> 1) << 6;
  const int wn = (wave & 1) << 6;

  const int srow   = lane >> 2;                                  // row within 16-row stage
  const int schunk = (((lane & 3) ^ ((lane >> 3) & 3)) << 3);    // swizzled k-chunk (elements)

  f32x4 acc[4][4];
  const f32x4 z4 = {0.f, 0.f, 0.f, 0.f};
  #pragma unroll
  for (int i = 0; i < 4; ++i)
    #pragma unroll
    for (int j = 0; j < 4; ++j) acc[i][j] = z4;

  const __bf16* Ab = A  + (size_t)bm * K;
  const __bf16* Bb = Bt + (size_t)bn * K;
  const int nk = K >> 5;

  #define STAGE(buf, kb)                                                              \
    {                                                                                 \
      const int k0s = (kb) << 5;                                                      \
      _Pragma("unroll")                                                               \
      for (int c = 0; c < 2; ++c) {                                                   \
        const int cc = wave * 2 + c;                                                  \
        g2lds16(Ab + (size_t)(cc * 16 + srow) * K + k0s + schunk, &Asm[buf][cc * 512]);\
        g2lds16(Bb + (size_t)(cc * 16 + srow) * K + k0s + schunk, &Bsm[buf][cc * 512]);\
      }                                                                               \
    }

  STAGE(0, 0)
  int cur = 0;
  for (int kb = 0; kb < nk; ++kb) {
    __syncthreads();
    if (kb + 1 < nk) STAGE(cur ^ 1, kb + 1)
    bf16x8 af[4], bg[4];
    #pragma unroll
    for (int i = 0; i < 4; ++i) {
      int m = wm + i * 16 + l16;
      af[i] = *(const bf16x8*)(&Asm[cur][m * 32 + ((quad ^ ((m >> 1) & 3)) << 3)]);
    }
    #pragma unroll
    for (int j = 0; j < 4; ++j) {
      int n = wn + j * 16 + l16;
      bg[j] = *(const bf16x8*)(&Bsm[cur][n * 32 + ((quad ^ ((n >> 1) & 3)) << 3)]);
    }
    #pragma unroll
    for (int i = 0; i < 4; ++i)
      #pragma unroll
      for (int j = 0; j < 4; ++j)
        acc[i][j] = __builtin_amdgcn_mfma_f32_16x16x32_bf16(af[i], bg[j], acc[i][j], 0, 0, 0);
    cur ^= 1;
  }
  #undef STAGE

  // epilogue. C/D layout: col = lane&15, row = quad*4 + reg  [m89-verified]
  const bool dosig = (epi == 1) && (bn >= 512);
  #pragma unroll
  for (int j = 0; j < 4; ++j) {
    const int col = wn + j * 16 + l16;
    const float bv = bias[bn + col];
    #pragma unroll
    for (int i = 0; i < 4; ++i) {
      const int row0 = bm + wm + i * 16 + quad * 4;
      #pragma unroll
      for (int r = 0; r < 4; ++r) {
        float v = acc[i][j][r] + bv;
        if (epi == 1) {
          if (dosig) {
            v = 1.f / (1.f + expf(-v));
            C1[(size_t)(row0 + r) * 512 + (bn - 512) + col] = (__bf16)v;
          } else {
            C1b[(size_t)(row0 + r) * 512 + bn + col] = (__bf16)v;
          }
        } else {
          size_t off = (size_t)(row0 + r) * N + bn + col;
          if (epi == 2) v += res[off];
          C0[off] = v;
        }
      }
    }
  }
}

// ---------------- fp32 -> bf16 elementwise (tokens) ----------------
__global__ __launch_bounds__(256) void cvt_k(const float* __restrict__ s, __bf16* __restrict__ d)
{
  size_t i = ((size_t)blockIdx.x * 256 + threadIdx.x) * 8;
  float4 a = *(const float4*)(s + i);
  float4 b = *(const float4*)(s + i + 4);
  bf16x8 v;
  v[0] = (__bf16)a.x; v[1] = (__bf16)a.y; v[2] = (__bf16)a.z; v[3] = (__bf16)a.w;
  v[4] = (__bf16)b.x; v[5] = (__bf16)b.y; v[6] = (__bf16)b.z; v[7] = (__bf16)b.w;
  *(bf16x8*)(d + i) = v;
}

// ---------------- transpose KxN fp32 -> NxK bf16 (weights) ----------------
__global__ __launch_bounds__(256) void tr_k(const float* __restrict__ src, __bf16* __restrict__ dst,
                                            int K, int N, size_t sstr, size_t dstr)
{
  __shared__ float t[32][33];
  const float* s = src + blockIdx.z * sstr;
  __bf16* d = dst + blockIdx.z * dstr;
  int n0 = blockIdx.x * 32, k0 = blockIdx.y * 32;
  int tx = threadIdx.x & 31, ty = threadIdx.x >> 5;   // 32x8
  #pragma unroll
  for (int i = 0; i < 4; ++i)
    t[ty + i * 8][tx] = s[(size_t)(k0 + ty + i * 8) * N + n0 + tx];
  __syncthreads();
  #pragma unroll
  for (int i = 0; i < 4; ++i)
    d[(size_t)(n0 + ty + i * 8) * K + k0 + tx] = (__bf16)t[tx][ty + i * 8];
}

// ---------------- LayerNorm over D=512, one wave per position, bf16 out ----------------
__global__ __launch_bounds__(256) void ln_k(const float* __restrict__ x, const float* __restrict__ w,
                                            const float* __restrict__ bv, __bf16* __restrict__ out)
{
  int gw = (blockIdx.x * 256 + threadIdx.x) >> 6;   // position
  int lane = threadIdx.x & 63;
  const float* xp = x + ((size_t)gw << 9) + lane * 8;
  float4 u0 = *(const float4*)xp;
  float4 u1 = *(const float4*)(xp + 4);
  float v[8] = {u0.x,u0.y,u0.z,u0.w,u1.x,u1.y,u1.z,u1.w};
  float s = 0.f;
  #pragma unroll
  for (int j = 0; j < 8; ++j) s += v[j];
  #pragma unroll
  for (int off = 32; off; off >>= 1) s += __shfl_xor(s, off, 64);
  float mu = s * (1.f/512.f);
  float q = 0.f;
  #pragma unroll
  for (int j = 0; j < 8; ++j) { float d = v[j] - mu; q += d*d; }
  #pragma unroll
  for (int off = 32; off; off >>= 1) q += __shfl_xor(q, off, 64);
  float rstd = rsqrtf(q * (1.f/512.f) + 1e-5f);
  int dch = lane * 8;
  float4 w0 = *(const float4*)(w + dch),  w1 = *(const float4*)(w + dch + 4);
  float4 b0 = *(const float4*)(bv + dch), b1 = *(const float4*)(bv + dch + 4);
  float wv[8] = {w0.x,w0.y,w0.z,w0.w,w1.x,w1.y,w1.z,w1.w};
  float bb[8] = {b0.x,b0.y,b0.z,b0.w,b1.x,b1.y,b1.z,b1.w};
  bf16x8 ov;
  #pragma unroll
  for (int j = 0; j < 8; ++j) ov[j] = (__bf16)((v[j] - mu) * rstd * wv[j] + bb[j]);
  *(bf16x8*)(out + ((size_t)gw << 9) + dch) = ov;
}

// ================= Fully-fused conv + 2D scan, chunk-interleaved (R13-proven) =================
// R12 proved fusion wins (+44 µs unfused); R13's net regression decomposes entirely to the
// GEMM change, with ~10-15 µs residual GAIN attributable to this kernel's 2x ILP interleave.
// LDS: T (xin tile -> partial park, 64 KB) + Y (u tile, 64 KB) + S (16 KB) = 144 KB, 1 wg/CU.
// Bounded unroll 4 everywhere (R9/R10: scheduler cross-loop load batching is the spiller).
__device__ __forceinline__ float sig_a(float al) {
  float a = 1.f / (1.f + expf(-al));
  return fminf(fmaxf(a, 1e-4f), 1.f - 1e-4f);
}

__global__ __launch_bounds__(512, 2) void scan2d_k(
    const __bf16* __restrict__ xin, const float* __restrict__ cw, const float* __restrict__ cb,
    const float* __restrict__ alog, const float* __restrict__ bvec, const float* __restrict__ cvec,
    const float* __restrict__ dvec, const __bf16* __restrict__ gate, __bf16* __restrict__ yo)
{
  __shared__ __bf16 T[32768];       // xin tile [pos][32 ch]; partial park in phase C. 64 KB
  __shared__ __bf16 Y[32768];       // u tile. 64 KB
  __shared__ float  S[4][32][32];   // chunk sums: rowF,rowB,colF,colB. 16 KB
  const int tid = threadIdx.x;
  const int cg  = blockIdx.x;       // channel group of 32
  const int b   = blockIdx.y;
  const int ch  = tid & 31;
  const int c0  = tid >> 5;         // 0..15; thread owns chunks c0 and c0+16
  const int c1  = c0 + 16;
  const int d   = (cg << 5) + ch;

  const float a   = sig_a(alog[d]);
  const float lna = logf(a);
  const float ia  = 1.f / a;
  const float bb  = bvec[d];
  const float sc  = 0.25f * cvec[d];
  const float dd  = dvec[d];

  const __bf16* ub = xin + ((size_t)b << 19) + (cg << 5);

  // ---- load xin tile: 8 x bf16x8 per thread, 16 B/lane coalesced ----
  #pragma unroll
  for (int i = 0; i < 8; ++i) {
    int flat = (tid + i * 512) << 3;
    int pos = flat >> 5;
    int c8  = flat & 31;
    *(bf16x8*)(T + flat) = *(const bf16x8*)(ub + (size_t)pos * 512 + c8);
  }
  // conv weights while loads are in flight
  float w00 = cw[(0 << 9) + d], w01 = cw[(1 << 9) + d], w02 = cw[(2 << 9) + d];
  float w10 = cw[(3 << 9) + d], w11 = cw[(4 << 9) + d], w12 = cw[(5 << 9) + d];
  float w20 = cw[(6 << 9) + d], w21 = cw[(7 << 9) + d], w22 = cw[(8 << 9) + d];
  const float cbv = cb[d];
  // scan bases (loop-invariant; direct expf avoids 0*inf at extreme a)
  const float A0f = expf((float)(c0 << 5) * lna),        R0f = expf((float)(c0 << 5) * -lna);
  const float A1f = expf((float)(c1 << 5) * lna),        R1f = expf((float)(c1 << 5) * -lna);
  const float A0b = expf((float)((31 - c0) << 5) * lna), R0b = expf((float)((31 - c0) << 5) * -lna);
  const float A1b = expf((float)((31 - c1) << 5) * lna), R1b = expf((float)((31 - c1) << 5) * -lna);
  __syncthreads();

  // ---- phase 0: depthwise 3x3 conv + SiLU, rows c0 & c1 interleaved -> Y ----
  {
    const bool up0 = (c0 > 0);      // row c0-1 valid (c0+1 always <= 16 valid)
    const bool dn1 = (c0 < 15);     // row c1+1 valid (c1-1 always >= 15 valid)
    float a0 = 0.f, a1 = 0.f, a2 = 0.f, f0 = 0.f, f1 = 0.f, f2 = 0.f;   // col -1
    float b0 = up0 ? (float)T[(((c0 - 1) << 5)) * 32 + ch] : 0.f;        // col 0
    float b1 =        (float)T[((c0 << 5)) * 32 + ch];
    float b2 =        (float)T[(((c0 + 1) << 5)) * 32 + ch];
    float g0 =        (float)T[(((c1 - 1) << 5)) * 32 + ch];
    float g1 =        (float)T[((c1 << 5)) * 32 + ch];
    float g2 = dn1 ? (float)T[(((c1 + 1) << 5)) * 32 + ch] : 0.f;
    #pragma unroll 4
    for (int ww = 0; ww < 32; ++ww) {
      float e0 = 0.f, e1 = 0.f, e2 = 0.f, i0 = 0.f, i1 = 0.f, i2 = 0.f;  // col ww+1
      if (ww < 31) {
        e0 = up0 ? (float)T[(((c0 - 1) << 5) + ww + 1) * 32 + ch] : 0.f;
        e1 =        (float)T[((c0 << 5) + ww + 1) * 32 + ch];
        e2 =        (float)T[(((c0 + 1) << 5) + ww + 1) * 32 + ch];
        i0 =        (float)T[(((c1 - 1) << 5) + ww + 1) * 32 + ch];
        i1 =        (float)T[((c1 << 5) + ww + 1) * 32 + ch];
        i2 = dn1 ? (float)T[(((c1 + 1) << 5) + ww + 1) * 32 + ch] : 0.f;
      }
      float acc0 = cbv, acc1 = cbv;
      acc0 = fmaf(a0, w00, acc0); acc0 = fmaf(b0, w01, acc0); acc0 = fmaf(e0, w02, acc0);
      acc0 = fmaf(a1, w10, acc0); acc0 = fmaf(b1, w11, acc0); acc0 = fmaf(e1, w12, acc0);
      acc0 = fmaf(a2, w20, acc0); acc0 = fmaf(b2, w21, acc0); acc0 = fmaf(e2, w22, acc0);
      acc1 = fmaf(f0, w00, acc1); acc1 = fmaf(g0, w01, acc1); acc1 = fmaf(i0, w02, acc1);
      acc1 = fmaf(f1, w10, acc1); acc1 = fmaf(g1, w11, acc1); acc1 = fmaf(i1, w12, acc1);
      acc1 = fmaf(f2, w20, acc1); acc1 = fmaf(g2, w21, acc1); acc1 = fmaf(i2, w22, acc1);
      acc0 = acc0 / (1.f + expf(-acc0));
      acc1 = acc1 / (1.f + expf(-acc1));
      Y[((c0 << 5) + ww) * 32 + ch] = (__bf16)acc0;
      Y[((c1 << 5) + ww) * 32 + ch] = (__bf16)acc1;
      a0 = b0; a1 = b1; a2 = b2; b0 = e0; b1 = e1; b2 = e2;
      f0 = g0; f1 = g1; f2 = g2; g0 = i0; g1 = i1; g2 = i2;
    }
  }
  __syncthreads();

  // one scan step: r += u*bb/max(apr,1e-20) with tracked reciprocal
  #define STEP(r_, uu_, apr_, rp_)                                 \
    { float rr_ = (apr_ < 1e-20f) ? 1e20f : rp_;                   \
      r_ = fmaf((uu_) * bb, rr_, r_); }

  // ---- phase A: 8 chunk sums (2 chunks x rowF/rowB/colF/colB) in one loop ----
  {
    float p0 = A0f, q0 = R0f, p0B = A0b, q0B = R0b;
    float p1 = A1f, q1 = R1f, p1B = A1b, q1B = R1b;
    float s0 = 0.f, s1 = 0.f, s2 = 0.f, s3 = 0.f;
    float s4 = 0.f, s5 = 0.f, s6 = 0.f, s7 = 0.f;
    #pragma unroll 4
    for (int j = 0; j < 32; ++j) {
      float u0rf = (float)Y[((c0 << 5) + j) * 32 + ch];
      float u0rb = (float)Y[((c0 << 5) + (31 - j)) * 32 + ch];
      float u0cf = (float)Y[((j << 5) | c0) * 32 + ch];
      float u0cb = (float)Y[(((31 - j) << 5) | c0) * 32 + ch];
      float u1rf = (float)Y[((c1 << 5) + j) * 32 + ch];
      float u1rb = (float)Y[((c1 << 5) + (31 - j)) * 32 + ch];
      float u1cf = (float)Y[((j << 5) | c1) * 32 + ch];
      float u1cb = (float)Y[(((31 - j) << 5) | c1) * 32 + ch];
      STEP(s0, u0rf, p0, q0)  STEP(s2, u0cf, p0, q0)
      STEP(s1, u0rb, p0B, q0B) STEP(s3, u0cb, p0B, q0B)
      STEP(s4, u1rf, p1, q1)  STEP(s6, u1cf, p1, q1)
      STEP(s5, u1rb, p1B, q1B) STEP(s7, u1cb, p1B, q1B)
      p0 *= a; q0 *= ia; p0B *= a; q0B *= ia;
      p1 *= a; q1 *= ia; p1B *= a; q1B *= ia;
    }
    S[0][c0][ch] = s0; S[1][c0][ch] = s1; S[2][c0][ch] = s2; S[3][c0][ch] = s3;
    S[0][c1][ch] = s4; S[1][c1][ch] = s5; S[2][c1][ch] = s6; S[3][c1][ch] = s7;
  }
  __syncthreads();

  // ---- phase B: exclusive prefix (F arrays) / exclusive suffix (B arrays) ----
  if (tid < 128) {
    int arr = tid >> 5, ch2 = tid & 31;
    float run = 0.f;
    if ((arr & 1) == 0) {
      #pragma unroll 4
      for (int cc = 0; cc < 32; ++cc) { float v = S[arr][cc][ch2]; S[arr][cc][ch2] = run; run += v; }
    } else {
      #pragma unroll 4
      for (int cc = 31; cc >= 0; --cc) { float v = S[arr][cc][ch2]; S[arr][cc][ch2] = run; run += v; }
    }
  }
  __syncthreads();

  // ---- C-col fwd (both chunks): raw partial -> T ----
  {
    float r0 = S[2][c0][ch], r1 = S[2][c1][ch];
    float p0 = A0f, q0 = R0f, p1 = A1f, q1 = R1f;
    #pragma unroll 4
    for (int j = 0; j < 32; ++j) {
      int i0 = ((j << 5) | c0) * 32 + ch, i1 = ((j << 5) | c1) * 32 + ch;
      float u0 = (float)Y[i0], u1 = (float)Y[i1];
      float ap0 = fmaxf(p0, 1e-20f), ap1 = fmaxf(p1, 1e-20f);
      STEP(r0, u0, p0, q0) STEP(r1, u1, p1, q1)
      T[i0] = (__bf16)(r0 * ap0);
      T[i1] = (__bf16)(r1 * ap1);
      p0 *= a; q0 *= ia; p1 *= a; q1 *= ia;
    }
  }
  // ---- C-col bwd (both chunks): T = sc*(T + r*ap)  [same-thread RMW] ----
  {
    float r0 = S[3][c0][ch], r1 = S[3][c1][ch];
    float p0 = A0b, q0 = R0b, p1 = A1b, q1 = R1b;
    #pragma unroll 4
    for (int j = 31; j >= 0; --j) {
      int i0 = ((j << 5) | c0) * 32 + ch, i1 = ((j << 5) | c1) * 32 + ch;
      float u0 = (float)Y[i0], u1 = (float)Y[i1];
      float ap0 = fmaxf(p0, 1e-20f), ap1 = fmaxf(p1, 1e-20f);
      STEP(r0, u0, p0, q0) STEP(r1, u1, p1, q1)
      T[i0] = (__bf16)(sc * ((float)T[i0] + r0 * ap0));
      T[i1] = (__bf16)(sc * ((float)T[i1] + r1 * ap1));
      p0 *= a; q0 *= ia; p1 *= a; q1 *= ia;
    }
  }
  __syncthreads();   // row threads read other threads' col finals

  // ---- C-row fwd (both chunks): T += sc*(r*ap) ----
  {
    float r0 = S[0][c0][ch], r1 = S[0][c1][ch];
    float p0 = A0f, q0 = R0f, p1 = A1f, q1 = R1f;
    #pragma unroll 4
    for (int j = 0; j < 32; ++j) {
      int i0 = ((c0 << 5) + j) * 32 + ch, i1 = ((c1 << 5) + j) * 32 + ch;
      float u0 = (float)Y[i0], u1 = (float)Y[i1];
      float ap0 = fmaxf(p0, 1e-20f), ap1 = fmaxf(p1, 1e-20f);
      STEP(r0, u0, p0, q0) STEP(r1, u1, p1, q1)
      T[i0] = (__bf16)((float)T[i0] + sc * (r0 * ap0));
      T[i1] = (__bf16)((float)T[i1] + sc * (r1 * ap1));
      p0 *= a; q0 *= ia; p1 *= a; q1 *= ia;
    }
  }
  // ---- C-row bwd (both chunks): finalize + d*u, *gate, write out ----
  {
    const __bf16* gb = gate + ((size_t)b << 19) + (cg << 5) + ch;
    __bf16* yb = yo + ((size_t)b << 19) + (cg << 5) + ch;
    float r0 = S[1][c0][ch], r1 = S[1][c1][ch];
    float p0 = A0b, q0 = R0b, p1 = A1b, q1 = R1b;
    #pragma unroll 4
    for (int j = 31; j >= 0; --j) {
      int pp0 = (c0 << 5) + j, pp1 = (c1 << 5) + j;
      int i0 = pp0 * 32 + ch, i1 = pp1 * 32 + ch;
      float u0 = (float)Y[i0], u1 = (float)Y[i1];
      float ap0 = fmaxf(p0, 1e-20f), ap1 = fmaxf(p1, 1e-20f);
      STEP(r0, u0, p0, q0) STEP(r1, u1, p1, q1)
      float y0 = (float)T[i0] + sc * (r0 * ap0) + dd * u0;
      float y1 = (float)T[i1] + sc * (r1 * ap1) + dd * u1;
      yb[(size_t)pp0 * 512] = (__bf16)(y0 * (float)gb[(size_t)pp0 * 512]);
      yb[(size_t)pp1 * 512] = (__bf16)(y1 * (float)gb[(size_t)pp1 * 512]);
      p0 *= a; q0 *= ia; p1 *= a; q1 *= ia;
    }
  }
  #undef STEP
}

// ---------------- mean over 1024 positions (bf16 in) -> (16, 512) fp32 ----------------
// 256-thread blocks: thread (l, q) sums quarter q of positions for channel l; LDS reduce.
__global__ __launch_bounds__(256) void reduce_k(const __bf16* __restrict__ hn, float* __restrict__ out)
{
  __shared__ float part[4][64];
  int l = threadIdx.x & 63;       // channel within group
  int q = threadIdx.x >> 6;       // position quarter
  int d = blockIdx.y * 64 + l;
  int b = blockIdx.x;
  const __bf16* p = hn + ((size_t)b << 19) + d + ((size_t)(q * 256) << 9);
  float s0 = 0.f, s1 = 0.f, s2 = 0.f, s3 = 0.f;
  for (int t = 0; t < 256; t += 4) {
    s0 += (float)p[(size_t)(t+0) << 9];
    s1 += (float)p[(size_t)(t+1) << 9];
    s2 += (float)p[(size_t)(t+2) << 9];
    s3 += (float)p[(size_t)(t+3) << 9];
  }
  part[q][l] = (s0 + s1) + (s2 + s3);
  __syncthreads();
  if (threadIdx.x < 64)
    out[b * 512 + d] = (part[0][l] + part[1][l] + part[2][l] + part[3][l]) * (1.f / 1024.f);
}

extern "C" void kernel_launch(void* const* d_in, const int* in_sizes, int n_in,
                              void* d_out, int out_size, void* d_ws, size_t ws_size,
                              hipStream_t stream)
{
  const float* tokens = (const float*)d_in[0];
  const float* in_w   = (const float*)d_in[1];
  const float* in_b   = (const float*)d_in[2];
  const float* nw     = (const float*)d_in[3];
  const float* nb     = (const float*)d_in[4];
  const float* iw     = (const float*)d_in[5];
  const float* ib     = (const float*)d_in[6];
  const float* cw     = (const float*)d_in[7];
  const float* cb     = (const float*)d_in[8];
  const float* al     = (const float*)d_in[9];
  const float* bbv    = (const float*)d_in[10];
  const float* ccv    = (const float*)d_in[11];
  const float* ddv    = (const float*)d_in[12];
  const float* ow     = (const float*)d_in[13];
  const float* obv    = (const float*)d_in[14];
  const float* onw    = (const float*)d_in[15];
  const float* onb    = (const float*)d_in[16];

  // workspace layout (~115 MB):
  float*  x     = (float*)d_ws;                      // fp32 residual (33.5 MB)
  __bf16* hy16  = (__bf16*)(x + PP);                 // bf16 h / yg / final-ln (16.8 MB)
  __bf16* xin16 = hy16 + PP;                         // bf16 x_in (16.8 MB)
  __bf16* g16   = xin16 + PP;                        // bf16 gate (16.8 MB)
  __bf16* iwT   = g16 + PP;                          // 4x(1024x512) bf16 (4.2 MB)
  __bf16* owT   = iwT + (size_t)4 * 1024 * 512;      // 4x(512x512) bf16 (2.1 MB)
  __bf16* tb16  = owT + (size_t)4 * 512 * 512;       // tokens bf16 (25.2 MB)
  __bf16* inwT  = xin16;                             // in_proj_w^T bf16 (pre-loop alias)

  // --- weight/input conversion (once per launch) ---
  cvt_k<<<6144, 256, 0, stream>>>(tokens, tb16);
  tr_k<<<dim3(16, 24, 1), 256, 0, stream>>>(in_w, inwT, 768, 512, 0, 0);
  tr_k<<<dim3(32, 16, 4), 256, 0, stream>>>(iw, iwT, 512, 1024, (size_t)512*1024, (size_t)1024*512);
  tr_k<<<dim3(16, 16, 4), 256, 0, stream>>>(ow, owT, 512, 512, (size_t)512*512, (size_t)512*512);

  // x = tokens @ in_proj_w + b   (grid: M-tiles fastest)
  gemm_bf_k<<<dim3(128, 4), 256, 0, stream>>>(tb16, inwT, in_b, nullptr, x, nullptr, nullptr,
                                              512, 768, 0);

  for (int i = 0; i < 4; ++i) {
    ln_k<<<4096, 256, 0, stream>>>(x, nw + i*512, nb + i*512, hy16);
    gemm_bf_k<<<dim3(128, 8), 256, 0, stream>>>(hy16, iwT + (size_t)i*1024*512, ib + i*1024,
                                                nullptr, nullptr, g16, xin16, 1024, 512, 1);
    scan2d_k<<<dim3(16, 16), 512, 0, stream>>>(xin16, cw + i*9*512, cb + i*512,
                                               al + i*512, bbv + i*512, ccv + i*512,
                                               ddv + i*512, g16, hy16);
    gemm_bf_k<<<dim3(128, 4), 256, 0, stream>>>(hy16, owT + (size_t)i*512*512, obv + i*512,
                                                x, x, nullptr, nullptr, 512, 512, 2);
  }

  ln_k<<<4096, 256, 0, stream>>>(x, onw, onb, hy16);
  reduce_k<<<dim3(16, 8), 256, 0, stream>>>(hy16, (float*)d_out);
}

// Round 15
// 635.557 us; speedup vs baseline: 1.2090x; 1.0251x over previous
//
#include <hip/hip_runtime.h>
#include <hip/hip_bf16.h>
#include <math.h>

#define NPOS 16384   // B*H*W = 16*32*32
#define DD   512
#define PP   ((size_t)NPOS * DD)   // 8388608 elements per plane

typedef __bf16 bf16x8 __attribute__((ext_vector_type(8)));
typedef __bf16 bf16x4 __attribute__((ext_vector_type(4)));
typedef float  f32x4  __attribute__((ext_vector_type(4)));

// ================= bf16 MFMA GEMM, 128x128, register-staged pipeline =================
// R14 counters: global_load_lds staging stalls on the s_waitcnt vmcnt(0) the compiler
// must emit before s_barrier (DMA's "use" IS the barrier). hipBLASLt-style escape:
// stage through REGISTERS (global->VGPR->ds_write). The vmcnt wait then attaches to
// the ds_write (the use), placed AFTER the MFMA block -> global latency (L2-resident
// B after XCD swizzle, ~200cyc) hides behind compute; barrier drains only lgkmcnt.
// Pipeline: GLOAD(kb+1) issued one iter ahead; iter kb = MFMA(buf cur) -> DSWRITE(cur^1)
// -> GLOAD(kb+2) -> barrier. LDS layout + XOR swizzle identical to R14 (frag reads
// conflict-free: LDS[r][slot] = G[r][slot ^ ((r>>1)&3)]).
// Grid: blockIdx.x = M-tile (fastest) -> A-sharers same XCD (R11/R12-verified).
// epi 0: C0 fp32 (ld N) = acc + bias
// epi 1: N=1024; cols<512 -> C1b bf16 (ld 512); cols>=512 -> sigmoid -> C1 bf16 (ld 512)
// epi 2: C0 fp32 (ld N) = acc + bias + res
__global__ __launch_bounds__(256, 3) void gemm_bf_k(
    const __bf16* __restrict__ A, const __bf16* __restrict__ Bt,
    const float* __restrict__ bias, const float* __restrict__ res,
    float* __restrict__ C0, __bf16* __restrict__ C1, __bf16* __restrict__ C1b,
    int N, int K, int epi)
{
  __shared__ __bf16 Asm[2][128 * 32];
  __shared__ __bf16 Bsm[2][128 * 32];
  const int tid  = threadIdx.x;
  const int wave = tid >> 6;
  const int lane = tid & 63;
  const int quad = lane >> 4;
  const int l16  = lane & 15;
  const int bm = blockIdx.x * 128;   // M fastest -> A-sharers on same XCD
  const int bn = blockIdx.y * 128;
  const int wm = (wave >> 1) << 6;
  const int wn = (wave & 1) << 6;

  // staging map: thread t handles rows r0=t>>2, r1=r0+64; LDS slot sl=t&3;
  // global col chunk ca = (t&3) ^ ((r0>>1)&3)  [same swizzle for r1: +64 ≡ 0 mod 4]
  const int r0 = tid >> 2;
  const int r1 = r0 + 64;
  const int sl = (tid & 3) << 3;                          // LDS slot offset (elements)
  const int ca = (((tid & 3) ^ ((r0 >> 1) & 3)) << 3);    // global col offset (elements)

  f32x4 acc[4][4];
  const f32x4 z4 = {0.f, 0.f, 0.f, 0.f};
  #pragma unroll
  for (int i = 0; i < 4; ++i)
    #pragma unroll
    for (int j = 0; j < 4; ++j) acc[i][j] = z4;

  const __bf16* Ab = A  + (size_t)bm * K;
  const __bf16* Bb = Bt + (size_t)bn * K;
  const int nk = K >> 5;

  bf16x8 ar0, ar1, br0, br1;        // staging registers (16 VGPRs)

  #define GLOAD(kb)                                                      \
    {                                                                    \
      const int k0s = (kb) << 5;                                         \
      ar0 = *(const bf16x8*)(Ab + (size_t)r0 * K + k0s + ca);            \
      ar1 = *(const bf16x8*)(Ab + (size_t)r1 * K + k0s + ca);            \
      br0 = *(const bf16x8*)(Bb + (size_t)r0 * K + k0s + ca);            \
      br1 = *(const bf16x8*)(Bb + (size_t)r1 * K + k0s + ca);            \
    }
  #define DSWRITE(buf)                                                   \
    {                                                                    \
      *(bf16x8*)(&Asm[buf][r0 * 32 + sl]) = ar0;                         \
      *(bf16x8*)(&Asm[buf][r1 * 32 + sl]) = ar1;                         \
      *(bf16x8*)(&Bsm[buf][r0 * 32 + sl]) = br0;                         \
      *(bf16x8*)(&Bsm[buf][r1 * 32 + sl]) = br1;                         \
    }

  GLOAD(0)
  DSWRITE(0)                         // prologue: full latency exposed once
  if (nk > 1) GLOAD(1)
  __syncthreads();

  int cur = 0;
  for (int kb = 0; kb < nk; ++kb) {
    // compute from buf[cur]
    bf16x8 af[4], bg[4];
    #pragma unroll
    for (int i = 0; i < 4; ++i) {
      int m = wm + i * 16 + l16;
      af[i] = *(const bf16x8*)(&Asm[cur][m * 32 + ((quad ^ ((m >> 1) & 3)) << 3)]);
    }
    #pragma unroll
    for (int j = 0; j < 4; ++j) {
      int n = wn + j * 16 + l16;
      bg[j] = *(const bf16x8*)(&Bsm[cur][n * 32 + ((quad ^ ((n >> 1) & 3)) << 3)]);
    }
    #pragma unroll
    for (int i = 0; i < 4; ++i)
      #pragma unroll
      for (int j = 0; j < 4; ++j)
        acc[i][j] = __builtin_amdgcn_mfma_f32_16x16x32_bf16(af[i], bg[j], acc[i][j], 0, 0, 0);
    // stage next tile: vmcnt wait lands here (after MFMA), not at the barrier
    if (kb + 1 < nk) {
      DSWRITE(cur ^ 1)               // tile kb+1 (regs loaded one iter ago)
      if (kb + 2 < nk) GLOAD(kb + 2)
    }
    __syncthreads();
    cur ^= 1;
  }
  #undef GLOAD
  #undef DSWRITE

  // epilogue. C/D layout: col = lane&15, row = quad*4 + reg  [m89-verified]
  const bool dosig = (epi == 1) && (bn >= 512);
  #pragma unroll
  for (int j = 0; j < 4; ++j) {
    const int col = wn + j * 16 + l16;
    const float bv = bias[bn + col];
    #pragma unroll
    for (int i = 0; i < 4; ++i) {
      const int row0 = bm + wm + i * 16 + quad * 4;
      #pragma unroll
      for (int r = 0; r < 4; ++r) {
        float v = acc[i][j][r] + bv;
        if (epi == 1) {
          if (dosig) {
            v = 1.f / (1.f + expf(-v));
            C1[(size_t)(row0 + r) * 512 + (bn - 512) + col] = (__bf16)v;
          } else {
            C1b[(size_t)(row0 + r) * 512 + bn + col] = (__bf16)v;
          }
        } else {
          size_t off = (size_t)(row0 + r) * N + bn + col;
          if (epi == 2) v += res[off];
          C0[off] = v;
        }
      }
    }
  }
}

// ---------------- fp32 -> bf16 elementwise (tokens) ----------------
__global__ __launch_bounds__(256) void cvt_k(const float* __restrict__ s, __bf16* __restrict__ d)
{
  size_t i = ((size_t)blockIdx.x * 256 + threadIdx.x) * 8;
  float4 a = *(const float4*)(s + i);
  float4 b = *(const float4*)(s + i + 4);
  bf16x8 v;
  v[0] = (__bf16)a.x; v[1] = (__bf16)a.y; v[2] = (__bf16)a.z; v[3] = (__bf16)a.w;
  v[4] = (__bf16)b.x; v[5] = (__bf16)b.y; v[6] = (__bf16)b.z; v[7] = (__bf16)b.w;
  *(bf16x8*)(d + i) = v;
}

// ---------------- transpose KxN fp32 -> NxK bf16 (weights) ----------------
__global__ __launch_bounds__(256) void tr_k(const float* __restrict__ src, __bf16* __restrict__ dst,
                                            int K, int N, size_t sstr, size_t dstr)
{
  __shared__ float t[32][33];
  const float* s = src + blockIdx.z * sstr;
  __bf16* d = dst + blockIdx.z * dstr;
  int n0 = blockIdx.x * 32, k0 = blockIdx.y * 32;
  int tx = threadIdx.x & 31, ty = threadIdx.x >> 5;   // 32x8
  #pragma unroll
  for (int i = 0; i < 4; ++i)
    t[ty + i * 8][tx] = s[(size_t)(k0 + ty + i * 8) * N + n0 + tx];
  __syncthreads();
  #pragma unroll
  for (int i = 0; i < 4; ++i)
    d[(size_t)(n0 + ty + i * 8) * K + k0 + tx] = (__bf16)t[tx][ty + i * 8];
}

// ---------------- LayerNorm over D=512, one wave per position, bf16 out ----------------
__global__ __launch_bounds__(256) void ln_k(const float* __restrict__ x, const float* __restrict__ w,
                                            const float* __restrict__ bv, __bf16* __restrict__ out)
{
  int gw = (blockIdx.x * 256 + threadIdx.x) >> 6;   // position
  int lane = threadIdx.x & 63;
  const float* xp = x + ((size_t)gw << 9) + lane * 8;
  float4 u0 = *(const float4*)xp;
  float4 u1 = *(const float4*)(xp + 4);
  float v[8] = {u0.x,u0.y,u0.z,u0.w,u1.x,u1.y,u1.z,u1.w};
  float s = 0.f;
  #pragma unroll
  for (int j = 0; j < 8; ++j) s += v[j];
  #pragma unroll
  for (int off = 32; off; off >>= 1) s += __shfl_xor(s, off, 64);
  float mu = s * (1.f/512.f);
  float q = 0.f;
  #pragma unroll
  for (int j = 0; j < 8; ++j) { float d = v[j] - mu; q += d*d; }
  #pragma unroll
  for (int off = 32; off; off >>= 1) q += __shfl_xor(q, off, 64);
  float rstd = rsqrtf(q * (1.f/512.f) + 1e-5f);
  int dch = lane * 8;
  float4 w0 = *(const float4*)(w + dch),  w1 = *(const float4*)(w + dch + 4);
  float4 b0 = *(const float4*)(bv + dch), b1 = *(const float4*)(bv + dch + 4);
  float wv[8] = {w0.x,w0.y,w0.z,w0.w,w1.x,w1.y,w1.z,w1.w};
  float bb[8] = {b0.x,b0.y,b0.z,b0.w,b1.x,b1.y,b1.z,b1.w};
  bf16x8 ov;
  #pragma unroll
  for (int j = 0; j < 8; ++j) ov[j] = (__bf16)((v[j] - mu) * rstd * wv[j] + bb[j]);
  *(bf16x8*)(out + ((size_t)gw << 9) + dch) = ov;
}

// ================= Fully-fused conv + 2D scan, chunk-interleaved (R13/R14-proven) =================
__device__ __forceinline__ float sig_a(float al) {
  float a = 1.f / (1.f + expf(-al));
  return fminf(fmaxf(a, 1e-4f), 1.f - 1e-4f);
}

__global__ __launch_bounds__(512, 2) void scan2d_k(
    const __bf16* __restrict__ xin, const float* __restrict__ cw, const float* __restrict__ cb,
    const float* __restrict__ alog, const float* __restrict__ bvec, const float* __restrict__ cvec,
    const float* __restrict__ dvec, const __bf16* __restrict__ gate, __bf16* __restrict__ yo)
{
  __shared__ __bf16 T[32768];       // xin tile [pos][32 ch]; partial park in phase C. 64 KB
  __shared__ __bf16 Y[32768];       // u tile. 64 KB
  __shared__ float  S[4][32][32];   // chunk sums: rowF,rowB,colF,colB. 16 KB
  const int tid = threadIdx.x;
  const int cg  = blockIdx.x;       // channel group of 32
  const int b   = blockIdx.y;
  const int ch  = tid & 31;
  const int c0  = tid >> 5;         // 0..15; thread owns chunks c0 and c0+16
  const int c1  = c0 + 16;
  const int d   = (cg << 5) + ch;

  const float a   = sig_a(alog[d]);
  const float lna = logf(a);
  const float ia  = 1.f / a;
  const float bb  = bvec[d];
  const float sc  = 0.25f * cvec[d];
  const float dd  = dvec[d];

  const __bf16* ub = xin + ((size_t)b << 19) + (cg << 5);

  // ---- load xin tile: 8 x bf16x8 per thread, 16 B/lane coalesced ----
  #pragma unroll
  for (int i = 0; i < 8; ++i) {
    int flat = (tid + i * 512) << 3;
    int pos = flat >> 5;
    int c8  = flat & 31;
    *(bf16x8*)(T + flat) = *(const bf16x8*)(ub + (size_t)pos * 512 + c8);
  }
  // conv weights while loads are in flight
  float w00 = cw[(0 << 9) + d], w01 = cw[(1 << 9) + d], w02 = cw[(2 << 9) + d];
  float w10 = cw[(3 << 9) + d], w11 = cw[(4 << 9) + d], w12 = cw[(5 << 9) + d];
  float w20 = cw[(6 << 9) + d], w21 = cw[(7 << 9) + d], w22 = cw[(8 << 9) + d];
  const float cbv = cb[d];
  // scan bases (loop-invariant; direct expf avoids 0*inf at extreme a)
  const float A0f = expf((float)(c0 << 5) * lna),        R0f = expf((float)(c0 << 5) * -lna);
  const float A1f = expf((float)(c1 << 5) * lna),        R1f = expf((float)(c1 << 5) * -lna);
  const float A0b = expf((float)((31 - c0) << 5) * lna), R0b = expf((float)((31 - c0) << 5) * -lna);
  const float A1b = expf((float)((31 - c1) << 5) * lna), R1b = expf((float)((31 - c1) << 5) * -lna);
  __syncthreads();

  // ---- phase 0: depthwise 3x3 conv + SiLU, rows c0 & c1 interleaved -> Y ----
  {
    const bool up0 = (c0 > 0);      // row c0-1 valid (c0+1 always <= 16 valid)
    const bool dn1 = (c0 < 15);     // row c1+1 valid (c1-1 always >= 15 valid)
    float a0 = 0.f, a1 = 0.f, a2 = 0.f, f0 = 0.f, f1 = 0.f, f2 = 0.f;   // col -1
    float b0 = up0 ? (float)T[(((c0 - 1) << 5)) * 32 + ch] : 0.f;        // col 0
    float b1 =        (float)T[((c0 << 5)) * 32 + ch];
    float b2 =        (float)T[(((c0 + 1) << 5)) * 32 + ch];
    float g0 =        (float)T[(((c1 - 1) << 5)) * 32 + ch];
    float g1 =        (float)T[((c1 << 5)) * 32 + ch];
    float g2 = dn1 ? (float)T[(((c1 + 1) << 5)) * 32 + ch] : 0.f;
    #pragma unroll 4
    for (int ww = 0; ww < 32; ++ww) {
      float e0 = 0.f, e1 = 0.f, e2 = 0.f, i0 = 0.f, i1 = 0.f, i2 = 0.f;  // col ww+1
      if (ww < 31) {
        e0 = up0 ? (float)T[(((c0 - 1) << 5) + ww + 1) * 32 + ch] : 0.f;
        e1 =        (float)T[((c0 << 5) + ww + 1) * 32 + ch];
        e2 =        (float)T[(((c0 + 1) << 5) + ww + 1) * 32 + ch];
        i0 =        (float)T[(((c1 - 1) << 5) + ww + 1) * 32 + ch];
        i1 =        (float)T[((c1 << 5) + ww + 1) * 32 + ch];
        i2 = dn1 ? (float)T[(((c1 + 1) << 5) + ww + 1) * 32 + ch] : 0.f;
      }
      float acc0 = cbv, acc1 = cbv;
      acc0 = fmaf(a0, w00, acc0); acc0 = fmaf(b0, w01, acc0); acc0 = fmaf(e0, w02, acc0);
      acc0 = fmaf(a1, w10, acc0); acc0 = fmaf(b1, w11, acc0); acc0 = fmaf(e1, w12, acc0);
      acc0 = fmaf(a2, w20, acc0); acc0 = fmaf(b2, w21, acc0); acc0 = fmaf(e2, w22, acc0);
      acc1 = fmaf(f0, w00, acc1); acc1 = fmaf(g0, w01, acc1); acc1 = fmaf(i0, w02, acc1);
      acc1 = fmaf(f1, w10, acc1); acc1 = fmaf(g1, w11, acc1); acc1 = fmaf(i1, w12, acc1);
      acc1 = fmaf(f2, w20, acc1); acc1 = fmaf(g2, w21, acc1); acc1 = fmaf(i2, w22, acc1);
      acc0 = acc0 / (1.f + expf(-acc0));
      acc1 = acc1 / (1.f + expf(-acc1));
      Y[((c0 << 5) + ww) * 32 + ch] = (__bf16)acc0;
      Y[((c1 << 5) + ww) * 32 + ch] = (__bf16)acc1;
      a0 = b0; a1 = b1; a2 = b2; b0 = e0; b1 = e1; b2 = e2;
      f0 = g0; f1 = g1; f2 = g2; g0 = i0; g1 = i1; g2 = i2;
    }
  }
  __syncthreads();

  // one scan step: r += u*bb/max(apr,1e-20) with tracked reciprocal
  #define STEP(r_, uu_, apr_, rp_)                                 \
    { float rr_ = (apr_ < 1e-20f) ? 1e20f : rp_;                   \
      r_ = fmaf((uu_) * bb, rr_, r_); }

  // ---- phase A: 8 chunk sums (2 chunks x rowF/rowB/colF/colB) in one loop ----
  {
    float p0 = A0f, q0 = R0f, p0B = A0b, q0B = R0b;
    float p1 = A1f, q1 = R1f, p1B = A1b, q1B = R1b;
    float s0 = 0.f, s1 = 0.f, s2 = 0.f, s3 = 0.f;
    float s4 = 0.f, s5 = 0.f, s6 = 0.f, s7 = 0.f;
    #pragma unroll 4
    for (int j = 0; j < 32; ++j) {
      float u0rf = (float)Y[((c0 << 5) + j) * 32 + ch];
      float u0rb = (float)Y[((c0 << 5) + (31 - j)) * 32 + ch];
      float u0cf = (float)Y[((j << 5) | c0) * 32 + ch];
      float u0cb = (float)Y[(((31 - j) << 5) | c0) * 32 + ch];
      float u1rf = (float)Y[((c1 << 5) + j) * 32 + ch];
      float u1rb = (float)Y[((c1 << 5) + (31 - j)) * 32 + ch];
      float u1cf = (float)Y[((j << 5) | c1) * 32 + ch];
      float u1cb = (float)Y[(((31 - j) << 5) | c1) * 32 + ch];
      STEP(s0, u0rf, p0, q0)  STEP(s2, u0cf, p0, q0)
      STEP(s1, u0rb, p0B, q0B) STEP(s3, u0cb, p0B, q0B)
      STEP(s4, u1rf, p1, q1)  STEP(s6, u1cf, p1, q1)
      STEP(s5, u1rb, p1B, q1B) STEP(s7, u1cb, p1B, q1B)
      p0 *= a; q0 *= ia; p0B *= a; q0B *= ia;
      p1 *= a; q1 *= ia; p1B *= a; q1B *= ia;
    }
    S[0][c0][ch] = s0; S[1][c0][ch] = s1; S[2][c0][ch] = s2; S[3][c0][ch] = s3;
    S[0][c1][ch] = s4; S[1][c1][ch] = s5; S[2][c1][ch] = s6; S[3][c1][ch] = s7;
  }
  __syncthreads();

  // ---- phase B: exclusive prefix (F arrays) / exclusive suffix (B arrays) ----
  if (tid < 128) {
    int arr = tid >> 5, ch2 = tid & 31;
    float run = 0.f;
    if ((arr & 1) == 0) {
      #pragma unroll 4
      for (int cc = 0; cc < 32; ++cc) { float v = S[arr][cc][ch2]; S[arr][cc][ch2] = run; run += v; }
    } else {
      #pragma unroll 4
      for (int cc = 31; cc >= 0; --cc) { float v = S[arr][cc][ch2]; S[arr][cc][ch2] = run; run += v; }
    }
  }
  __syncthreads();

  // ---- C-col fwd (both chunks): raw partial -> T ----
  {
    float r0 = S[2][c0][ch], r1 = S[2][c1][ch];
    float p0 = A0f, q0 = R0f, p1 = A1f, q1 = R1f;
    #pragma unroll 4
    for (int j = 0; j < 32; ++j) {
      int i0 = ((j << 5) | c0) * 32 + ch, i1 = ((j << 5) | c1) * 32 + ch;
      float u0 = (float)Y[i0], u1 = (float)Y[i1];
      float ap0 = fmaxf(p0, 1e-20f), ap1 = fmaxf(p1, 1e-20f);
      STEP(r0, u0, p0, q0) STEP(r1, u1, p1, q1)
      T[i0] = (__bf16)(r0 * ap0);
      T[i1] = (__bf16)(r1 * ap1);
      p0 *= a; q0 *= ia; p1 *= a; q1 *= ia;
    }
  }
  // ---- C-col bwd (both chunks): T = sc*(T + r*ap)  [same-thread RMW] ----
  {
    float r0 = S[3][c0][ch], r1 = S[3][c1][ch];
    float p0 = A0b, q0 = R0b, p1 = A1b, q1 = R1b;
    #pragma unroll 4
    for (int j = 31; j >= 0; --j) {
      int i0 = ((j << 5) | c0) * 32 + ch, i1 = ((j << 5) | c1) * 32 + ch;
      float u0 = (float)Y[i0], u1 = (float)Y[i1];
      float ap0 = fmaxf(p0, 1e-20f), ap1 = fmaxf(p1, 1e-20f);
      STEP(r0, u0, p0, q0) STEP(r1, u1, p1, q1)
      T[i0] = (__bf16)(sc * ((float)T[i0] + r0 * ap0));
      T[i1] = (__bf16)(sc * ((float)T[i1] + r1 * ap1));
      p0 *= a; q0 *= ia; p1 *= a; q1 *= ia;
    }
  }
  __syncthreads();   // row threads read other threads' col finals

  // ---- C-row fwd (both chunks): T += sc*(r*ap) ----
  {
    float r0 = S[0][c0][ch], r1 = S[0][c1][ch];
    float p0 = A0f, q0 = R0f, p1 = A1f, q1 = R1f;
    #pragma unroll 4
    for (int j = 0; j < 32; ++j) {
      int i0 = ((c0 << 5) + j) * 32 + ch, i1 = ((c1 << 5) + j) * 32 + ch;
      float u0 = (float)Y[i0], u1 = (float)Y[i1];
      float ap0 = fmaxf(p0, 1e-20f), ap1 = fmaxf(p1, 1e-20f);
      STEP(r0, u0, p0, q0) STEP(r1, u1, p1, q1)
      T[i0] = (__bf16)((float)T[i0] + sc * (r0 * ap0));
      T[i1] = (__bf16)((float)T[i1] + sc * (r1 * ap1));
      p0 *= a; q0 *= ia; p1 *= a; q1 *= ia;
    }
  }
  // ---- C-row bwd (both chunks): finalize + d*u, *gate, write out ----
  {
    const __bf16* gb = gate + ((size_t)b << 19) + (cg << 5) + ch;
    __bf16* yb = yo + ((size_t)b << 19) + (cg << 5) + ch;
    float r0 = S[1][c0][ch], r1 = S[1][c1][ch];
    float p0 = A0b, q0 = R0b, p1 = A1b, q1 = R1b;
    #pragma unroll 4
    for (int j = 31; j >= 0; --j) {
      int pp0 = (c0 << 5) + j, pp1 = (c1 << 5) + j;
      int i0 = pp0 * 32 + ch, i1 = pp1 * 32 + ch;
      float u0 = (float)Y[i0], u1 = (float)Y[i1];
      float ap0 = fmaxf(p0, 1e-20f), ap1 = fmaxf(p1, 1e-20f);
      STEP(r0, u0, p0, q0) STEP(r1, u1, p1, q1)
      float y0 = (float)T[i0] + sc * (r0 * ap0) + dd * u0;
      float y1 = (float)T[i1] + sc * (r1 * ap1) + dd * u1;
      yb[(size_t)pp0 * 512] = (__bf16)(y0 * (float)gb[(size_t)pp0 * 512]);
      yb[(size_t)pp1 * 512] = (__bf16)(y1 * (float)gb[(size_t)pp1 * 512]);
      p0 *= a; q0 *= ia; p1 *= a; q1 *= ia;
    }
  }
  #undef STEP
}

// ---------------- mean over 1024 positions (bf16 in) -> (16, 512) fp32 ----------------
// 256-thread blocks: thread (l, q) sums quarter q of positions for channel l; LDS reduce.
__global__ __launch_bounds__(256) void reduce_k(const __bf16* __restrict__ hn, float* __restrict__ out)
{
  __shared__ float part[4][64];
  int l = threadIdx.x & 63;       // channel within group
  int q = threadIdx.x >> 6;       // position quarter
  int d = blockIdx.y * 64 + l;
  int b = blockIdx.x;
  const __bf16* p = hn + ((size_t)b << 19) + d + ((size_t)(q * 256) << 9);
  float s0 = 0.f, s1 = 0.f, s2 = 0.f, s3 = 0.f;
  for (int t = 0; t < 256; t += 4) {
    s0 += (float)p[(size_t)(t+0) << 9];
    s1 += (float)p[(size_t)(t+1) << 9];
    s2 += (float)p[(size_t)(t+2) << 9];
    s3 += (float)p[(size_t)(t+3) << 9];
  }
  part[q][l] = (s0 + s1) + (s2 + s3);
  __syncthreads();
  if (threadIdx.x < 64)
    out[b * 512 + d] = (part[0][l] + part[1][l] + part[2][l] + part[3][l]) * (1.f / 1024.f);
}

extern "C" void kernel_launch(void* const* d_in, const int* in_sizes, int n_in,
                              void* d_out, int out_size, void* d_ws, size_t ws_size,
                              hipStream_t stream)
{
  const float* tokens = (const float*)d_in[0];
  const float* in_w   = (const float*)d_in[1];
  const float* in_b   = (const float*)d_in[2];
  const float* nw     = (const float*)d_in[3];
  const float* nb     = (const float*)d_in[4];
  const float* iw     = (const float*)d_in[5];
  const float* ib     = (const float*)d_in[6];
  const float* cw     = (const float*)d_in[7];
  const float* cb     = (const float*)d_in[8];
  const float* al     = (const float*)d_in[9];
  const float* bbv    = (const float*)d_in[10];
  const float* ccv    = (const float*)d_in[11];
  const float* ddv    = (const float*)d_in[12];
  const float* ow     = (const float*)d_in[13];
  const float* obv    = (const float*)d_in[14];
  const float* onw    = (const float*)d_in[15];
  const float* onb    = (const float*)d_in[16];

  // workspace layout (~115 MB):
  float*  x     = (float*)d_ws;                      // fp32 residual (33.5 MB)
  __bf16* hy16  = (__bf16*)(x + PP);                 // bf16 h / yg / final-ln (16.8 MB)
  __bf16* xin16 = hy16 + PP;                         // bf16 x_in (16.8 MB)
  __bf16* g16   = xin16 + PP;                        // bf16 gate (16.8 MB)
  __bf16* iwT   = g16 + PP;                          // 4x(1024x512) bf16 (4.2 MB)
  __bf16* owT   = iwT + (size_t)4 * 1024 * 512;      // 4x(512x512) bf16 (2.1 MB)
  __bf16* tb16  = owT + (size_t)4 * 512 * 512;       // tokens bf16 (25.2 MB)
  __bf16* inwT  = xin16;                             // in_proj_w^T bf16 (pre-loop alias)

  // --- weight/input conversion (once per launch) ---
  cvt_k<<<6144, 256, 0, stream>>>(tokens, tb16);
  tr_k<<<dim3(16, 24, 1), 256, 0, stream>>>(in_w, inwT, 768, 512, 0, 0);
  tr_k<<<dim3(32, 16, 4), 256, 0, stream>>>(iw, iwT, 512, 1024, (size_t)512*1024, (size_t)1024*512);
  tr_k<<<dim3(16, 16, 4), 256, 0, stream>>>(ow, owT, 512, 512, (size_t)512*512, (size_t)512*512);

  // x = tokens @ in_proj_w + b   (grid: M-tiles fastest)
  gemm_bf_k<<<dim3(128, 4), 256, 0, stream>>>(tb16, inwT, in_b, nullptr, x, nullptr, nullptr,
                                              512, 768, 0);

  for (int i = 0; i < 4; ++i) {
    ln_k<<<4096, 256, 0, stream>>>(x, nw + i*512, nb + i*512, hy16);
    gemm_bf_k<<<dim3(128, 8), 256, 0, stream>>>(hy16, iwT + (size_t)i*1024*512, ib + i*1024,
                                                nullptr, nullptr, g16, xin16, 1024, 512, 1);
    scan2d_k<<<dim3(16, 16), 512, 0, stream>>>(xin16, cw + i*9*512, cb + i*512,
                                               al + i*512, bbv + i*512, ccv + i*512,
                                               ddv + i*512, g16, hy16);
    gemm_bf_k<<<dim3(128, 4), 256, 0, stream>>>(hy16, owT + (size_t)i*512*512, obv + i*512,
                                                x, x, nullptr, nullptr, 512, 512, 2);
  }

  ln_k<<<4096, 256, 0, stream>>>(x, onw, onb, hy16);
  reduce_k<<<dim3(16, 8), 256, 0, stream>>>(hy16, (float*)d_out);
}